// Round 1
// baseline (156.761 us; speedup 1.0000x reference)
//
#include <hip/hip_runtime.h>
#include <math.h>

#define BATCH 4
#define CH    256   // feature channels == depth of sampled volume
#define HH    128
#define WW    128
#define PC    256   // para channels
#define PI_F  3.14159f
#define PLANE (HH * WW)   // 16384 floats

// Padded LDS plane: rows -1..129 (index y+1 in [0,130]), cols -1..132.
// Stride 134 words: 134 mod 32 = 6 -> linear lane-walks spread banks.
// Border + padding cells hold 0.0f, zeroed once at kernel start: OOB
// sampling reads stored zeros => padding_mode='zeros' with NO mask VALU.
#define PSTRIDE 134
#define PROWS   131
#define BUFSZ   (PROWS * PSTRIDE)   // 17554 words = 70216 B

// Light barrier: drains LDS ops only (lgkmcnt), NOT vmcnt — the plane's
// global staging loads stay in flight across the params phase.
__device__ __forceinline__ void barrier_lds() {
    asm volatile("s_waitcnt lgkmcnt(0)\n\ts_barrier" ::: "memory");
}

struct Stage { float4 a[4]; float4 b[4]; };

__device__ __forceinline__ Stage stage_load(const float* __restrict__ pl0,
                                            const float* __restrict__ pl1, int t) {
    Stage s;
#pragma unroll
    for (int j = 0; j < 4; ++j) {
        const int f = 4 * (t + 1024 * j);
        s.a[j] = *(const float4*)(pl0 + f);
        s.b[j] = *(const float4*)(pl1 + f);
    }
    return s;
}

// z-combine + scatter into padded layout (interior cells only; border cells
// remain zero). 4 consecutive floats -> compiler merges to ds_write2_b32.
__device__ __forceinline__ void stage_store_pad(float* __restrict__ buf, const Stage& s,
                                                float wz0, float wz1, int t) {
#pragma unroll
    for (int j = 0; j < 4; ++j) {
        const int f = 4 * (t + 1024 * j);
        const int y = f >> 7, x = f & (WW - 1);
        float* p = &buf[(y + 1) * PSTRIDE + (x + 1)];
        p[0] = fmaf(wz0, s.a[j].x, wz1 * s.b[j].x);
        p[1] = fmaf(wz0, s.a[j].y, wz1 * s.b[j].y);
        p[2] = fmaf(wz0, s.a[j].z, wz1 * s.b[j].z);
        p[3] = fmaf(wz0, s.a[j].w, wz1 * s.b[j].w);
    }
}

// ---------------------------------------------------------------------------
// One plane per block (NP=1), 1024 blocks x 1024 threads, SINGLE padded LDS
// buffer (75.4 KiB total static LDS) => 2 blocks/CU resident, 32 waves/CU.
// Cross-block overlap replaces the old intra-block double buffer: while one
// block waits on its staging vmcnt / barriers, the co-resident block's 16
// waves gather+store. __launch_bounds__(1024,8): 8 waves/EU => VGPR<=64
// (current build is 52, fits without spill).
// ---------------------------------------------------------------------------
__global__ __launch_bounds__(1024, 8)
void adaat_fused_kernel(const float* __restrict__ fm,
                        const float* __restrict__ pc,
                        const float* __restrict__ W1, const float* __restrict__ b1,
                        const float* __restrict__ Ws, const float* __restrict__ bs,
                        const float* __restrict__ Wr, const float* __restrict__ br,
                        const float* __restrict__ Wt, const float* __restrict__ bt,
                        float* __restrict__ out) {
    __shared__ float  lds[BUFSZ];       // 70.2 KiB single padded plane
    __shared__ float  red[1024];        // GEMV reduce scratch (4 KiB)
    __shared__ float  p_sh[PC];
    __shared__ float  sh_head[4];
    __shared__ float4 sh_par;

    const int t = threadIdx.x;

    // XCD-chunked swizzle (grid 1024 = 8 XCDs x 128, bijective): HW deals
    // blockIdx round-robin over XCDs; remap so each XCD owns a CONTIGUOUS
    // channel range -> adjacent channels (which share a source plane) hit
    // the same per-XCD L2 instead of bouncing through LLC.
    const int bid = blockIdx.x;
    const int lc  = ((bid & 7) << 7) | (bid >> 3);   // logical (batch,channel)
    const int b   = lc >> 8;
    const int c   = lc & (CH - 1);

    // block-uniform staging constants (scalarized)
    const float* base = fm + (size_t)b * (CH * PLANE);
    const float  iz = (256.0f / 255.0f) * (float)c - 0.5f;
    const float  zf = floorf(iz);
    const float  fz = iz - zf;
    const int    z0 = (int)zf;
    const float  w0 = (z0 >= 0)     ? (1.0f - fz) : 0.0f;
    const float  w1 = (z0 + 1 < CH) ? fz          : 0.0f;
    const float* pl0 = base + (size_t)max(z0, 0)          * PLANE;
    const float* pl1 = base + (size_t)min(z0 + 1, CH - 1) * PLANE;

    // ---- 1) plane staging loads in flight through all of params ----
    Stage s = stage_load(pl0, pl1, t);

    // ---- 2) zero the padded buffer (borders must read 0.0f) ----
#pragma unroll
    for (int i = 0; i < 18; ++i) {
        const int idx = t + 1024 * i;
        if (idx < BUFSZ) lds[idx] = 0.0f;
    }

    // ---- 3) p = relu(pc @ W1 + b1), 4-way k-split ----
    {
        const int jj = t & 255, kk = t >> 8;
        const float* pcb = pc + b * PC + kk * 64;
        const float* w   = W1 + (kk * 64) * PC + jj;
        float acc = 0.0f;
#pragma unroll 8
        for (int i = 0; i < 64; ++i)
            acc = fmaf(pcb[i], w[i * PC], acc);
        red[t] = acc;
    }
    barrier_lds();
    if (t < 256)
        p_sh[t] = fmaxf(red[t] + red[256 + t] + red[512 + t] + red[768 + t] + b1[t], 0.0f);
    barrier_lds();   // p_sh visible; zeroing drained

    // ---- 4) store plane into LDS (waits only its own vmcnt) ----
    stage_store_pad(lds, s, w0, w1, t);

    // ---- 5) head dots: wave wv in [0,4) -> head wv for this channel ----
    const int wv = t >> 6, l = t & 63;
    if (wv < 4) {
        const float* wp; int stride;
        if      (wv == 0) { wp = Ws + c;               stride = PC;     }
        else if (wv == 1) { wp = Wr + c;               stride = PC;     }
        else              { wp = Wt + 2 * c + (wv == 3); stride = 2 * PC; }
        float dot = 0.0f;
#pragma unroll
        for (int m = 0; m < 4; ++m) {
            const int k = l + 64 * m;
            dot = fmaf(p_sh[k], wp[(size_t)k * stride], dot);
        }
#pragma unroll
        for (int off = 32; off >= 1; off >>= 1)
            dot += __shfl_xor(dot, off, 64);
        if (l == 0) sh_head[wv] = dot;
    }
    barrier_lds();

    // ---- 6) transcendentals -> fused padded-pixel-space constants ----
    if (t == 0) {
        const float s2  = 2.0f / (1.0f + expf(-(sh_head[0] + bs[c])));
        const float ang = tanhf(sh_head[1] + br[c]) * PI_F;
        float sa, ca;
        sincosf(ang, &sa, &ca);
        const float A  = s2 * ca, B = s2 * sa;
        const float Tx = tanhf(sh_head[2] + bt[2 * c]);
        const float Ty = tanhf(sh_head[3] + bt[2 * c + 1]);
        sh_par = make_float4(A * (128.0f / 127.0f),
                             B * (128.0f / 127.0f),
                             64.0f * (Tx - A + B) + 64.5f,   // +1 border bias
                             64.0f * (Ty - A - B) + 64.5f);
    }
    barrier_lds();   // sh_par + plane stores visible

    // ---- 7) gather: wave wv owns rows [8wv, 8wv+8), lane = column ----
    // Store pattern: 64 lanes write 64 CONSECUTIVE dwords (256 B, 2 cache
    // lines per instruction) vs the old 8-row scatter (8 lines/instr).
    // Clamp coord into [0, 129.99]: far-OOB pixels land entirely on zero
    // cells; edge pixels get the exact zero-padded bilinear weights.
    {
        const float4 P  = sh_par;
        const float  cA = P.x, cB = P.y;
        float* outp = out + (size_t)lc * PLANE;
        const float xf0 = (float)l;
        float rowf = (float)(wv * 8);
#pragma unroll 2
        for (int r = 0; r < 8; ++r) {
            const float bx = fmaf(-cB, rowf, P.z);   // per-row partials
            const float by = fmaf( cA, rowf, P.w);
            float* orow = outp + (wv * 8 + r) * WW;
#pragma unroll
            for (int h = 0; h < 2; ++h) {
                const float xf  = xf0 + 64.0f * h;
                const float ix  = fmaf(cA, xf, bx);
                const float iy  = fmaf(cB, xf, by);
                const float xc  = fminf(fmaxf(ix, 0.0f), 129.99f);
                const float yc  = fminf(fmaxf(iy, 0.0f), 129.99f);
                const float x0f = floorf(xc), y0f = floorf(yc);
                const float fx  = xc - x0f,   fy  = yc - y0f;
                const int   a   = (int)y0f * PSTRIDE + (int)x0f;
                const float v00 = lds[a],           v01 = lds[a + 1];           // ds_read2
                const float v10 = lds[a + PSTRIDE], v11 = lds[a + PSTRIDE + 1]; // ds_read2
                const float h0  = fmaf(fx, v01 - v00, v00);
                const float h1  = fmaf(fx, v11 - v10, v10);
                orow[h * 64 + l] = fmaf(fy, h1 - h0, h0);
            }
            rowf += 1.0f;
        }
    }
}

// ---------------------------------------------------------------------------
extern "C" void kernel_launch(void* const* d_in, const int* in_sizes, int n_in,
                              void* d_out, int out_size, void* d_ws, size_t ws_size,
                              hipStream_t stream) {
    const float* feature_map = (const float*)d_in[0];  // [4,256,128,128]
    const float* para_code   = (const float*)d_in[1];  // [4,256]
    const float* W1 = (const float*)d_in[2];
    const float* b1 = (const float*)d_in[3];
    const float* Ws = (const float*)d_in[4];
    const float* bs = (const float*)d_in[5];
    const float* Wr = (const float*)d_in[6];
    const float* br = (const float*)d_in[7];
    const float* Wt = (const float*)d_in[8];
    const float* bt = (const float*)d_in[9];

    adaat_fused_kernel<<<BATCH * CH, 1024, 0, stream>>>(
        feature_map, para_code, W1, b1, Ws, bs, Wr, br, Wt, bt, (float*)d_out);
}